// Round 4
// baseline (610.560 us; speedup 1.0000x reference)
//
#include <hip/hip_runtime.h>

// ADI diffusion B=16, C=8, S=128, 10 steps. Round 13: all 10 steps fused in
// ONE plain kernel with a hand-rolled grid barrier (round-3's cooperative
// launch was silently rejected under graph capture -> output stayed zero).
// Geometry = proven round-9 kernel (179us, absmax 0.0156): 256 blocks x 512
// threads, 129KB LDS -> exactly 1 block/CU on 256 CUs => all blocks
// co-resident by construction; grid barrier is deadlock-safe.
// Barrier: counter+generation, agent-scope atomics (cross-XCD coherent),
// __threadfence() for L2 writeback/invalidate of the ping-pong stores.

constexpr int S_ = 128;
constexpr int RS = 129;             // padded LDS row stride
constexpr float EPSF = 1e-6f;
constexpr int NBLK = 256;

// LDS regions (floats): A: head 96-row tile / owned 64-row tile
//                       B: head x@0 out / x1 park
//                       C: x-coeff (co) 64 rows
constexpr int OFF_A = 0;
constexpr int OFF_B = 12384;        // 96*129
constexpr int OFF_C = 24768;
constexpr int POOL  = 33024;        // ~129 KB

__device__ unsigned g_cnt = 0;
__device__ unsigned g_gen = 0;

__device__ __forceinline__ void gridbar() {
    __syncthreads();                 // drains vmcnt: block's stores are in L2
    if (threadIdx.x == 0) {
        __threadfence();             // wbl2: push this XCD's dirty L2 down
        unsigned gen = __hip_atomic_load(&g_gen, __ATOMIC_RELAXED,
                                         __HIP_MEMORY_SCOPE_AGENT);
        unsigned old = __hip_atomic_fetch_add(&g_cnt, 1u, __ATOMIC_ACQ_REL,
                                              __HIP_MEMORY_SCOPE_AGENT);
        if (old == NBLK - 1) {
            __hip_atomic_store(&g_cnt, 0u, __ATOMIC_RELAXED,
                               __HIP_MEMORY_SCOPE_AGENT);
            __hip_atomic_fetch_add(&g_gen, 1u, __ATOMIC_RELEASE,
                                   __HIP_MEMORY_SCOPE_AGENT);
        } else {
            while (__hip_atomic_load(&g_gen, __ATOMIC_RELAXED,
                                     __HIP_MEMORY_SCOPE_AGENT) == gen)
                __builtin_amdgcn_s_sleep(8);
        }
        __threadfence();             // inv: drop stale L2 lines before reads
    }
    __syncthreads();
}

__device__ __forceinline__ void jrun(const float (&e)[12], const float (&g)[12],
                                     float (&o)[8]) {
    float x1[12];
    #pragma unroll
    for (int i = 1; i <= 10; ++i) x1[i] = fmaf(g[i], e[i - 1] + e[i + 1], e[i]);
    #pragma unroll
    for (int i = 2; i <= 9; ++i) o[i - 2] = fmaf(g[i], x1[i - 1] + x1[i + 1], e[i]);
}

__global__ __launch_bounds__(512, 2) void adi10_kernel(
    const float* __restrict__ u0, float* __restrict__ bws, float* __restrict__ bout,
    const float* __restrict__ ab, const float* __restrict__ atc,
    const float* __restrict__ bbeta, const float* __restrict__ btc,
    const float* __restrict__ cm)
{
    __shared__ float sP[POOL];
    const int tid = threadIdx.x;
    const int b   = blockIdx.x >> 4;
    const int h0  = (blockIdx.x & 15) << 3;
    const float dt2 = 0.0005f;

    for (int k = 0; k < 10; ++k) {
        const bool head = (k == 0);
        const bool tailmix = (k < 9);
        const float t_y = (2 * k + 1) * dt2;
        const float t_x = (2 * k + 2) * dt2;
        const float* src = head ? u0 : ((k & 1) ? bws : bout);
        float* dst = (k & 1) ? bout : bws;   // k odd -> out buffer; k=9 -> bout

        if (head) {
            // load 12-row tile (col layout: lanes contiguous in w)
            #pragma unroll
            for (int m = 0; m < 2; ++m) {
                const int col = tid + 512 * m;
                const int c = col >> 7, w = col & 127;
                #pragma unroll
                for (int hh = 0; hh < 12; ++hh) {
                    const int gh = h0 - 2 + hh;
                    float v = 0.f;
                    if (gh >= 0 && gh < S_) v = u0[((b * 8 + c) * S_ + gh) * S_ + w];
                    sP[OFF_A + (c * 12 + hh) * RS + w] = v;
                }
            }
            __syncthreads();
            // mix in place (each point owned by one thread)
            {
                float M[64];
                #pragma unroll
                for (int i = 0; i < 64; ++i) M[i] = cm[i];
                #pragma unroll
                for (int m = 0; m < 3; ++m) {
                    const int p = tid + 512 * m;
                    const int hh = p >> 7, w = p & 127;
                    float v[8], o[8];
                    #pragma unroll
                    for (int c = 0; c < 8; ++c) v[c] = sP[OFF_A + (c * 12 + hh) * RS + w];
                    #pragma unroll
                    for (int dd = 0; dd < 8; ++dd) {
                        float a = 0.f;
                        #pragma unroll
                        for (int c = 0; c < 8; ++c) a = fmaf(M[dd * 8 + c], v[c], a);
                        o[dd] = a;
                    }
                    #pragma unroll
                    for (int c = 0; c < 8; ++c) sP[OFF_A + (c * 12 + hh) * RS + w] = o[c];
                }
            }
            __syncthreads();
            // x@0 on 96 rows x 16 runs (alpha = clip(ab), t=0) -> OFF_B
            #pragma unroll
            for (int m = 0; m < 3; ++m) {
                const int run = tid + 512 * m;
                const int r96 = run % 96;
                const int wr  = run / 96;
                const int c = r96 / 12, hh = r96 % 12;
                const int gh = h0 - 2 + hh;
                const int w0 = wr * 8;
                const bool rowin = (gh >= 0 && gh < S_);
                float e[12], g[12];
                #pragma unroll
                for (int j = 0; j < 12; ++j) {
                    const int wj = w0 - 2 + j;
                    const bool win = (wj >= 0 && wj < S_);
                    const float dv = win ? sP[OFF_A + r96 * RS + wj] : 0.f;
                    float co = 0.f;
                    if (rowin && win) {
                        float al = ab[(c * S_ + gh) * S_ + wj];
                        al = fminf(fmaxf(al, EPSF), 10.f);
                        co = al * 0.0005f;
                    }
                    const float nb = (wj == 0 || wj == S_ - 1) ? 1.f : 2.f;
                    const float rb = __builtin_amdgcn_rcpf(fmaf(nb, co, 1.f) + EPSF);
                    e[j] = rb * dv; g[j] = rb * co;
                }
                float o[8]; jrun(e, g, o);
                #pragma unroll
                for (int i = 0; i < 8; ++i) sP[OFF_B + r96 * RS + w0 + i] = o[i];
            }
            __syncthreads();
        }

        // ---- Y stage: 1024 (c,w) columns, 2/thread; solve along h in regs.
        #pragma unroll
        for (int m = 0; m < 2; ++m) {
            const int col = tid + 512 * m;
            const int c = col >> 7, w = col & 127;
            float e[12], g[12];
            #pragma unroll
            for (int hh = 0; hh < 12; ++hh) {
                const int gh = h0 - 2 + hh;
                const bool inr = (gh >= 0 && gh < S_);
                const int ghc = inr ? gh : 0;
                float dv;
                if (head) dv = sP[OFF_B + (c * 12 + hh) * RS + w];
                else      dv = inr ? src[((b * 8 + c) * S_ + ghc) * S_ + w] : 0.f;
                const int gc = (c * S_ + ghc) * S_ + w;
                float be = fmaf(btc[gc], t_y, bbeta[gc]);
                be = fminf(fmaxf(be, EPSF), 10.f);
                const float co = inr ? be * 0.001f : 0.f;
                const float nb = (gh == 0 || gh == S_ - 1) ? 1.f : 2.f;
                const float rb = __builtin_amdgcn_rcpf(fmaf(nb, co, 1.f) + EPSF);
                e[hh] = rb * dv; g[hh] = rb * co;
            }
            float o[8]; jrun(e, g, o);
            #pragma unroll
            for (int i = 0; i < 8; ++i) sP[OFF_A + (c * 8 + i) * RS + w] = o[i];
        }
        // x-coeff into C (coalesced point layout)
        #pragma unroll
        for (int m = 0; m < 16; ++m) {
            const int p = tid + 512 * m;
            const int r = p >> 7, w = p & 127;
            const int c = r >> 3, ho = r & 7;
            const int gc = (c * S_ + h0 + ho) * S_ + w;
            float al = fmaf(atc[gc], t_x, ab[gc]);
            al = fminf(fmaxf(al, EPSF), 10.f);
            sP[OFF_C + r * RS + w] = al * 0.0005f;
        }
        __syncthreads();

        // ---- X1: 64 rows x 16 runs, 2/thread
        float rbk[2][12], gk[2][12], xo[2][8];
        #pragma unroll
        for (int m = 0; m < 2; ++m) {
            const int run = tid + 512 * m;
            const int r = run & 63, wr = run >> 6;
            const int w0 = wr * 8;
            float e[12];
            #pragma unroll
            for (int j = 0; j < 12; ++j) {
                const int wj = w0 - 2 + j;
                const bool win = (wj >= 0 && wj < S_);
                const float co = win ? sP[OFF_C + r * RS + wj] : 0.f;
                const float dv = win ? sP[OFF_A + r * RS + wj] : 0.f;
                const float nb = (wj == 0 || wj == S_ - 1) ? 1.f : 2.f;
                const float rb = __builtin_amdgcn_rcpf(fmaf(nb, co, 1.f) + EPSF);
                rbk[m][j] = rb; gk[m][j] = rb * co;
                e[j] = rb * dv;
            }
            jrun(e, gk[m], xo[m]);
        }

        if (tailmix) {
            #pragma unroll
            for (int m = 0; m < 2; ++m) {
                const int run = tid + 512 * m;
                const int r = run & 63, w0 = (run >> 6) * 8;
                #pragma unroll
                for (int i = 0; i < 8; ++i) sP[OFF_B + r * RS + w0 + i] = xo[m][i];
            }
            __syncthreads();
            // mix: 1024 points, 2/thread; read B, write A
            float M[64];
            #pragma unroll
            for (int i = 0; i < 64; ++i) M[i] = cm[i];
            #pragma unroll
            for (int m = 0; m < 2; ++m) {
                const int p = tid + 512 * m;
                const int ho = p >> 7, w = p & 127;
                float v[8], o[8];
                #pragma unroll
                for (int c = 0; c < 8; ++c) v[c] = sP[OFF_B + (c * 8 + ho) * RS + w];
                #pragma unroll
                for (int dd = 0; dd < 8; ++dd) {
                    float a = 0.f;
                    #pragma unroll
                    for (int c = 0; c < 8; ++c) a = fmaf(M[dd * 8 + c], v[c], a);
                    o[dd] = a;
                }
                #pragma unroll
                for (int c = 0; c < 8; ++c) sP[OFF_A + (c * 8 + ho) * RS + w] = o[c];
            }
            __syncthreads();
            // X2: same runs, same coeffs (same t)
            #pragma unroll
            for (int m = 0; m < 2; ++m) {
                const int run = tid + 512 * m;
                const int r = run & 63, wr = run >> 6;
                const int w0 = wr * 8;
                const int c = r >> 3, ho = r & 7;
                float e[12];
                #pragma unroll
                for (int j = 0; j < 12; ++j) {
                    const int wj = w0 - 2 + j;
                    const bool win = (wj >= 0 && wj < S_);
                    const float dv = win ? sP[OFF_A + r * RS + wj] : 0.f;
                    e[j] = rbk[m][j] * dv;
                }
                float o[8]; jrun(e, gk[m], o);
                float4* dst4 = (float4*)&dst[((b * 8 + c) * S_ + h0 + ho) * S_ + w0];
                dst4[0] = make_float4(o[0], o[1], o[2], o[3]);
                dst4[1] = make_float4(o[4], o[5], o[6], o[7]);
            }
        } else {
            #pragma unroll
            for (int m = 0; m < 2; ++m) {
                const int run = tid + 512 * m;
                const int r = run & 63, wr = run >> 6;
                const int w0 = wr * 8;
                const int c = r >> 3, ho = r & 7;
                float4* dst4 = (float4*)&dst[((b * 8 + c) * S_ + h0 + ho) * S_ + w0];
                dst4[0] = make_float4(xo[m][0], xo[m][1], xo[m][2], xo[m][3]);
                dst4[1] = make_float4(xo[m][4], xo[m][5], xo[m][6], xo[m][7]);
            }
        }

        if (k < 9) gridbar();   // cross-block halo dependency for next step
    }
}

extern "C" void kernel_launch(void* const* d_in, const int* in_sizes, int n_in,
                              void* d_out, int out_size, void* d_ws, size_t ws_size,
                              hipStream_t stream) {
    const float* u_in = (const float*)d_in[0];
    const float* ab   = (const float*)d_in[1];
    const float* bbta = (const float*)d_in[2];
    const float* atc  = (const float*)d_in[3];
    const float* btc  = (const float*)d_in[4];
    const float* cm   = (const float*)d_in[5];
    float* uo = (float*)d_out;
    float* uw = (float*)d_ws;     // 8 MB ping buffer

    adi10_kernel<<<dim3(NBLK), dim3(512), 0, stream>>>(u_in, uw, uo, ab, atc,
                                                       bbta, btc, cm);
}